// Round 2
// 322.199 us; speedup vs baseline: 1.0885x; 1.0885x over previous
//
#include <hip/hip_runtime.h>
#include <stdint.h>

// Problem constants (fixed by reference)
#define B_ROWS 8192
#define DH     1024      // D == H == 1024
#define KTOT   2048      // D + H (concatenated K)
#define NTOT   4096      // 4*H gate-interleaved columns

typedef __attribute__((ext_vector_type(8))) __bf16 bf16x8;
typedef __attribute__((ext_vector_type(4))) float  f32x4;

// ---------- helpers ----------
__device__ __forceinline__ unsigned short f2bf(float f) {
    unsigned int u = __float_as_uint(f);
    u += 0x7FFFu + ((u >> 16) & 1u);   // round-to-nearest-even
    return (unsigned short)(u >> 16);
}

__device__ __forceinline__ float fast_sigmoid(float x) {
    return 1.0f / (1.0f + __expf(-x));
}
__device__ __forceinline__ float fast_tanh(float x) {
    float e = __expf(fminf(-2.0f * x, 80.0f));   // clamp avoids inf/inf
    return (1.0f - e) / (1.0f + e);
}
__device__ __forceinline__ float sel4(float g0, float g1, float g2, float g3, int u) {
    float r = g0;
    r = (u == 1) ? g1 : r;
    r = (u == 2) ? g2 : r;
    r = (u == 3) ? g3 : r;
    return r;
}

// ---------- single fused pack kernel (unchanged, verified) ----------
#define NBLK_A (B_ROWS)            // one block packs one 2048-elem row
#define NBLK_W (NTOT)
#define NBLK_BIAS (NTOT / 256)

__global__ __launch_bounds__(256) void pack_all(const float* __restrict__ e_t,
                                                const float* __restrict__ h_prev,
                                                const float* __restrict__ W_x,
                                                const float* __restrict__ W_h,
                                                const float* __restrict__ b_x,
                                                const float* __restrict__ b_h,
                                                const float* __restrict__ b_e,
                                                unsigned short* __restrict__ A_cat,
                                                unsigned short* __restrict__ W_cat,
                                                float* __restrict__ bias) {
    const int blk = blockIdx.x;
    const int t   = threadIdx.x;
    if (blk < NBLK_A + NBLK_W) {
        const float* src0;
        unsigned short* dst;
        int row;
        if (blk < NBLK_A) {
            row = blk;
            dst = A_cat + (size_t)row * KTOT;
            int c8 = t << 3;
            src0 = (c8 < DH) ? (e_t + (size_t)row * DH + c8)
                             : (h_prev + (size_t)row * DH + (c8 - DH));
        } else {
            row = blk - NBLK_A;                 // g' = h*4 + gate
            int h = row >> 2, gate = row & 3;
            int srow = gate * DH + h;
            dst = W_cat + (size_t)row * KTOT;
            int c8 = t << 3;
            src0 = (c8 < DH) ? (W_x + (size_t)srow * DH + c8)
                             : (W_h + (size_t)srow * DH + (c8 - DH));
        }
        float4 f0 = ((const float4*)src0)[0];
        float4 f1 = ((const float4*)src0)[1];
        uint4 o;
        o.x = (unsigned)f2bf(f0.x) | ((unsigned)f2bf(f0.y) << 16);
        o.y = (unsigned)f2bf(f0.z) | ((unsigned)f2bf(f0.w) << 16);
        o.z = (unsigned)f2bf(f1.x) | ((unsigned)f2bf(f1.y) << 16);
        o.w = (unsigned)f2bf(f1.z) | ((unsigned)f2bf(f1.w) << 16);
        *(uint4*)(dst + t * 8) = o;
    } else {
        int gp = (blk - NBLK_A - NBLK_W) * 256 + t;   // g' in [0,4096)
        int h = gp >> 2, gate = gp & 3;
        int g = gate * DH + h;
        bias[gp] = b_x[g] + b_h[g] + b_e[g];
    }
}

// ---------- 256x256 8-wave 4-phase GEMM + fused LSTM epilogue ----------
//
// m201-class structure: T2 swizzle + T3 phase interleave + T4 counted vmcnt
// + T5 setprio.  BM=BN=256, BK=64, 8 waves (2M x 4N), LDS 128 KiB:
//   As[2 parity][256 rows][64 bf16] at 0 / 32K   (tile t uses parity t&1)
//   Bs[2 parity][256 rows][64 bf16] at 64K / 96K
// Row layout + XOR granule swizzle identical to the verified 128^2 kernel:
// logical 16B-granule g of row r stored at physical p = g ^ (r&7); applied
// on the global SOURCE address (global_load_lds dest stays linear);
// fragment reads use p = (kk*4+quad) ^ (lane15&7).
//
// REGION LIVENESS (the round-1 bug fix): fragment reads are NOT confined to
// half-tiles per phase (afl spans rows {0-63}u{128-191} across wm).  The
// only safe freeing points are:
//   - ALL B reads of tile t done after P2's trailing barrier -> stage B(t+2)
//     into Bs_cur in P3.
//   - ALL A reads of tile t done after P3's trailing barrier -> stage A(t+2)
//     into As_cur in P4.
// Staging always targets the CURRENT parity buffers (t+2 == t mod 2).
// P4 then waits vmcnt(8): exactly the 8 loads of tile t+2 stay in flight,
// so tile t+1 (staged during t-1) is fully resident before the P4 trailing
// barrier releases the next tile's reads.  vmcnt never drains to 0 in the
// main loop.

#define GLL(srcp, dstp) \
    __builtin_amdgcn_global_load_lds( \
        (const __attribute__((address_space(1))) void*)(srcp), \
        (__attribute__((address_space(3))) void*)(dstp), 16, 0, 0)

// one half-tile = 128 rows x 64 cols bf16 = 2 issues x (8 waves x 64 lanes x 16B)
#define STAGE_HALF(g, buf, h, kt) do { \
    GLL((g) + ((size_t)((h) * 128)      * KTOT) + (size_t)(kt) * 64, (buf) + (((h) * 128)      + w8) * 128); \
    GLL((g) + ((size_t)((h) * 128 + 64) * KTOT) + (size_t)(kt) * 64, (buf) + (((h) * 128 + 64) + w8) * 128); \
} while (0)

// mid-phase: pin reads/stages before barrier; drain this wave's LDS reads after
#define PHASE_MID() do { \
    __builtin_amdgcn_sched_barrier(0); \
    __builtin_amdgcn_s_barrier(); \
    asm volatile("s_waitcnt lgkmcnt(0)" ::: "memory"); \
    __builtin_amdgcn_sched_barrier(0); \
} while (0)

// trailing: pin MFMA cluster before barrier (barrier frees LDS read regions)
#define PHASE_END() do { \
    __builtin_amdgcn_sched_barrier(0); \
    __builtin_amdgcn_s_barrier(); \
    __builtin_amdgcn_sched_barrier(0); \
} while (0)

template <int MODE>  // 2 = steady  (stage B(t+2) in P3, A(t+2) in P4, vmcnt(8))
                     // 1 = tile 30 (no staging, vmcnt(0) drains tile 31)
                     // 0 = tile 31 (no staging, no vmcnt)
__device__ __forceinline__ void do_tile(
    int kt,
    unsigned char* As_cur, unsigned char* Bs_cur,
    const unsigned short* __restrict__ gA, const unsigned short* __restrict__ gB,
    int w8, int rowA, int rowB, int xg0, int xg1,
    f32x4 (&acc)[8][4])
{
    bf16x8 afl[4][2], afh[4][2], bfl[2][2], bfh[2][2];

    // ---- phase 1: read af_lo + bf_lo; MFMA lo x lo ----
#pragma unroll
    for (int mi = 0; mi < 4; ++mi) {
        afl[mi][0] = *(const bf16x8*)(As_cur + rowA + mi * 2048 + xg0);
        afl[mi][1] = *(const bf16x8*)(As_cur + rowA + mi * 2048 + xg1);
    }
#pragma unroll
    for (int ni = 0; ni < 2; ++ni) {
        bfl[ni][0] = *(const bf16x8*)(Bs_cur + rowB + ni * 2048 + xg0);
        bfl[ni][1] = *(const bf16x8*)(Bs_cur + rowB + ni * 2048 + xg1);
    }
    PHASE_MID();
    __builtin_amdgcn_s_setprio(1);
#pragma unroll
    for (int mi = 0; mi < 4; ++mi)
#pragma unroll
        for (int ni = 0; ni < 2; ++ni) {
            acc[mi][ni] = __builtin_amdgcn_mfma_f32_16x16x32_bf16(afl[mi][0], bfl[ni][0], acc[mi][ni], 0, 0, 0);
            acc[mi][ni] = __builtin_amdgcn_mfma_f32_16x16x32_bf16(afl[mi][1], bfl[ni][1], acc[mi][ni], 0, 0, 0);
        }
    __builtin_amdgcn_s_setprio(0);
    PHASE_END();

    // ---- phase 2: read bf_hi; MFMA lo x hi  (last B reads of this tile) ----
#pragma unroll
    for (int ni = 0; ni < 2; ++ni) {
        bfh[ni][0] = *(const bf16x8*)(Bs_cur + rowB + (2 + ni) * 2048 + xg0);
        bfh[ni][1] = *(const bf16x8*)(Bs_cur + rowB + (2 + ni) * 2048 + xg1);
    }
    PHASE_MID();
    __builtin_amdgcn_s_setprio(1);
#pragma unroll
    for (int mi = 0; mi < 4; ++mi)
#pragma unroll
        for (int ni = 0; ni < 2; ++ni) {
            acc[mi][2 + ni] = __builtin_amdgcn_mfma_f32_16x16x32_bf16(afl[mi][0], bfh[ni][0], acc[mi][2 + ni], 0, 0, 0);
            acc[mi][2 + ni] = __builtin_amdgcn_mfma_f32_16x16x32_bf16(afl[mi][1], bfh[ni][1], acc[mi][2 + ni], 0, 0, 0);
        }
    __builtin_amdgcn_s_setprio(0);
    PHASE_END();   // <- all B reads of tile kt retired in every wave

    // ---- phase 3: read af_hi; stage B(kt+2) -> Bs_cur; MFMA hi x lo ----
#pragma unroll
    for (int mi = 0; mi < 4; ++mi) {
        afh[mi][0] = *(const bf16x8*)(As_cur + rowA + (4 + mi) * 2048 + xg0);
        afh[mi][1] = *(const bf16x8*)(As_cur + rowA + (4 + mi) * 2048 + xg1);
    }
    if constexpr (MODE == 2) {
        STAGE_HALF(gB, Bs_cur, 0, kt + 2);
        STAGE_HALF(gB, Bs_cur, 1, kt + 2);
    }
    PHASE_MID();
    __builtin_amdgcn_s_setprio(1);
#pragma unroll
    for (int mi = 0; mi < 4; ++mi)
#pragma unroll
        for (int ni = 0; ni < 2; ++ni) {
            acc[4 + mi][ni] = __builtin_amdgcn_mfma_f32_16x16x32_bf16(afh[mi][0], bfl[ni][0], acc[4 + mi][ni], 0, 0, 0);
            acc[4 + mi][ni] = __builtin_amdgcn_mfma_f32_16x16x32_bf16(afh[mi][1], bfl[ni][1], acc[4 + mi][ni], 0, 0, 0);
        }
    __builtin_amdgcn_s_setprio(0);
    PHASE_END();   // <- all A reads of tile kt retired in every wave

    // ---- phase 4: stage A(kt+2) -> As_cur; counted vmcnt; MFMA hi x hi ----
    if constexpr (MODE == 2) {
        STAGE_HALF(gA, As_cur, 0, kt + 2);
        STAGE_HALF(gA, As_cur, 1, kt + 2);
        __builtin_amdgcn_sched_barrier(0);
        asm volatile("s_waitcnt vmcnt(8)" ::: "memory");   // tile kt+1 resident
        __builtin_amdgcn_sched_barrier(0);
    } else if constexpr (MODE == 1) {
        __builtin_amdgcn_sched_barrier(0);
        asm volatile("s_waitcnt vmcnt(0)" ::: "memory");   // tile 31 resident
        __builtin_amdgcn_sched_barrier(0);
    }
    PHASE_MID();
    __builtin_amdgcn_s_setprio(1);
#pragma unroll
    for (int mi = 0; mi < 4; ++mi)
#pragma unroll
        for (int ni = 0; ni < 2; ++ni) {
            acc[4 + mi][2 + ni] = __builtin_amdgcn_mfma_f32_16x16x32_bf16(afh[mi][0], bfh[ni][0], acc[4 + mi][2 + ni], 0, 0, 0);
            acc[4 + mi][2 + ni] = __builtin_amdgcn_mfma_f32_16x16x32_bf16(afh[mi][1], bfh[ni][1], acc[4 + mi][2 + ni], 0, 0, 0);
        }
    __builtin_amdgcn_s_setprio(0);
    PHASE_END();   // <- releases next tile's reads; tile kt+1 data landed
}

__global__ __launch_bounds__(512, 2) void lstm_gemm(
    const unsigned short* __restrict__ A,
    const unsigned short* __restrict__ Wc,
    const float* __restrict__ bias,
    const float* __restrict__ c_prev,
    float* __restrict__ h_out,
    float* __restrict__ c_out)
{
    __shared__ __align__(16) unsigned char lds[131072];

    const int tid = threadIdx.x;
    const int w   = tid >> 6;          // wave 0..7
    const int l   = tid & 63;          // lane
    const int wm  = w >> 2, wn = w & 3;
    const int m0  = blockIdx.y * 256;
    const int n0  = blockIdx.x * 256;
    const int w8  = w * 8;

    f32x4 acc[8][4];
#pragma unroll
    for (int i = 0; i < 8; ++i)
#pragma unroll
        for (int j = 0; j < 4; ++j) acc[i][j] = {0.f, 0.f, 0.f, 0.f};

    // staging: wave w, lane l -> tile row = base + w*8 + (l>>3),
    // physical granule p = l&7, pre-swizzled source granule g = p ^ (row&7)
    const int srow = w8 + (l >> 3);
    const int scol = ((l & 7) ^ ((l >> 3) & 7)) * 8;   // element offset in 64-wide K-tile
    const unsigned short* gA = A  + (size_t)(m0 + srow) * KTOT + scol;
    const unsigned short* gB = Wc + (size_t)(n0 + srow) * KTOT + scol;

    unsigned char* As0 = lds;
    unsigned char* As1 = lds + 32768;
    unsigned char* Bs0 = lds + 65536;
    unsigned char* Bs1 = lds + 98304;

    const int lane15 = l & 15;
    const int quad   = l >> 4;
    const int rowA = (wm * 128 + lane15) * 128;   // byte offset of A fragment row base
    const int rowB = (wn * 64  + lane15) * 128;
    const int xg0  = ((0 + quad) ^ (lane15 & 7)) * 16;   // kk=0 swizzled granule
    const int xg1  = ((4 + quad) ^ (lane15 & 7)) * 16;   // kk=1

    // ---- prologue: stage tile0 -> parity-0 bufs, tile1 -> parity-1 bufs ----
    STAGE_HALF(gA, As0, 0, 0);
    STAGE_HALF(gA, As0, 1, 0);
    STAGE_HALF(gB, Bs0, 0, 0);
    STAGE_HALF(gB, Bs0, 1, 0);
    STAGE_HALF(gA, As1, 0, 1);
    STAGE_HALF(gA, As1, 1, 1);
    STAGE_HALF(gB, Bs1, 0, 1);
    STAGE_HALF(gB, Bs1, 1, 1);
    asm volatile("s_waitcnt vmcnt(8)" ::: "memory");   // tile0 fully resident
    __builtin_amdgcn_s_barrier();

#pragma unroll 1
    for (int kt2 = 0; kt2 < 15; ++kt2) {
        do_tile<2>(2 * kt2,     As0, Bs0, gA, gB, w8, rowA, rowB, xg0, xg1, acc);
        do_tile<2>(2 * kt2 + 1, As1, Bs1, gA, gB, w8, rowA, rowB, xg0, xg1, acc);
    }
    do_tile<1>(30, As0, Bs0, gA, gB, w8, rowA, rowB, xg0, xg1, acc);
    do_tile<0>(31, As1, Bs1, gA, gB, w8, rowA, rowB, xg0, xg1, acc);

    // ---------- fused LSTM epilogue (verified gate-gather, 8x4 frags) ----------
    // C/D layout: col = lane&15 (n), row = quad*4 + reg (m).
    // Gate interleave: n = h*4 + gate -> gates of one h live in lane quads.
    float biasv[4];
#pragma unroll
    for (int nj = 0; nj < 4; ++nj)
        biasv[nj] = bias[n0 + wn * 64 + nj * 16 + lane15];

    const int u = (l >> 2) & 3;                 // reg (row-sub) this lane outputs
    const int v = l & 3;                        // h-sub this lane outputs
    const int src_base = (l & 0x30) | (v << 2); // quad-preserving gather base
    const int hbase = (n0 + wn * 64) >> 2;

#pragma unroll
    for (int mi = 0; mi < 8; ++mi) {
        const int m = m0 + wm * 128 + mi * 16 + quad * 4 + u;
#pragma unroll
        for (int nj = 0; nj < 4; ++nj) {
            f32x4 a = acc[mi][nj];
            float bb = biasv[nj];
            float a0 = a[0] + bb, a1 = a[1] + bb, a2 = a[2] + bb, a3 = a[3] + bb;

            float s0, s1, s2, s3;
            s0 = __shfl(a0, src_base | 0, 64); s1 = __shfl(a1, src_base | 0, 64);
            s2 = __shfl(a2, src_base | 0, 64); s3 = __shfl(a3, src_base | 0, 64);
            float zf = sel4(s0, s1, s2, s3, u);
            s0 = __shfl(a0, src_base | 1, 64); s1 = __shfl(a1, src_base | 1, 64);
            s2 = __shfl(a2, src_base | 1, 64); s3 = __shfl(a3, src_base | 1, 64);
            float zi = sel4(s0, s1, s2, s3, u);
            s0 = __shfl(a0, src_base | 2, 64); s1 = __shfl(a1, src_base | 2, 64);
            s2 = __shfl(a2, src_base | 2, 64); s3 = __shfl(a3, src_base | 2, 64);
            float zo = sel4(s0, s1, s2, s3, u);
            s0 = __shfl(a0, src_base | 3, 64); s1 = __shfl(a1, src_base | 3, 64);
            s2 = __shfl(a2, src_base | 3, 64); s3 = __shfl(a3, src_base | 3, 64);
            float zc = sel4(s0, s1, s2, s3, u);

            float gf = fast_sigmoid(zf);
            float gi = fast_sigmoid(zi);
            float go = fast_sigmoid(zo);
            float mh = fast_tanh(zc);

            const int h = hbase + nj * 4 + v;
            const size_t off = (size_t)m * DH + h;
            float cp = c_prev[off];
            float ct = gf * cp + gi * mh;
            float ht = go * fast_tanh(ct);
            h_out[off] = ht;
            c_out[off] = ct;
        }
    }
}

// ---------- launch ----------
extern "C" void kernel_launch(void* const* d_in, const int* in_sizes, int n_in,
                              void* d_out, int out_size, void* d_ws, size_t ws_size,
                              hipStream_t stream) {
    const float* e_t     = (const float*)d_in[0];
    const float* h_prev  = (const float*)d_in[1];
    const float* c_prev  = (const float*)d_in[2];
    const float* W_x     = (const float*)d_in[3];
    const float* b_x     = (const float*)d_in[4];
    const float* W_h     = (const float*)d_in[5];
    const float* b_h     = (const float*)d_in[6];
    const float* b_extra = (const float*)d_in[7];

    float* h_out = (float*)d_out;
    float* c_out = h_out + (size_t)B_ROWS * DH;

    // workspace layout: A_cat (32MB) | W_cat (16MB) | bias (16KB)
    unsigned short* A_cat = (unsigned short*)d_ws;
    unsigned short* W_cat = (unsigned short*)((char*)d_ws + (size_t)B_ROWS * KTOT * 2);
    float*          bias  = (float*)((char*)d_ws + (size_t)B_ROWS * KTOT * 2 + (size_t)NTOT * KTOT * 2);

    pack_all<<<NBLK_A + NBLK_W + NBLK_BIAS, 256, 0, stream>>>(
        e_t, h_prev, W_x, W_h, b_x, b_h, b_extra, A_cat, W_cat, bias);
    lstm_gemm<<<dim3(NTOT / 256, B_ROWS / 256), 512, 0, stream>>>(
        A_cat, W_cat, bias, c_prev, h_out, c_out);
}

// Round 3
// 295.654 us; speedup vs baseline: 1.1863x; 1.0898x over previous
//
#include <hip/hip_runtime.h>
#include <stdint.h>

// Problem constants (fixed by reference)
#define B_ROWS 8192
#define DH     1024      // D == H == 1024
#define KTOT   2048      // D + H (concatenated K)
#define NTOT   4096      // 4*H columns (gate-deinterleaved packing, see below)

typedef __attribute__((ext_vector_type(8))) __bf16 bf16x8;
typedef __attribute__((ext_vector_type(4))) float  f32x4;

// ---------- helpers ----------
__device__ __forceinline__ unsigned short f2bf(float f) {
    unsigned int u = __float_as_uint(f);
    u += 0x7FFFu + ((u >> 16) & 1u);   // round-to-nearest-even
    return (unsigned short)(u >> 16);
}

__device__ __forceinline__ float fast_sigmoid(float x) {
    return 1.0f / (1.0f + __expf(-x));
}
__device__ __forceinline__ float fast_tanh(float x) {
    float e = __expf(fminf(-2.0f * x, 80.0f));   // clamp avoids inf/inf
    return (1.0f - e) / (1.0f + e);
}

// ---------- single fused pack kernel ----------
// N-space packing (NEW, gate-deinterleaved for a shuffle-free epilogue):
//   W_cat row n holds W row g = gate*DH + h with
//     gate = (n>>4) & 3,  h = (n>>6)*16 + (n&15)
//   => for a fixed 64-wide n-block (one wave's wn slice), the four nj=0..3
//      sub-blocks are the four gates of the SAME 16 h values (h = base+lane15).
//   bias[] packed identically.  The GEMM is invariant to this column perm.
#define NBLK_A (B_ROWS)            // one block packs one 2048-elem row
#define NBLK_W (NTOT)
#define NBLK_BIAS (NTOT / 256)

__global__ __launch_bounds__(256) void pack_all(const float* __restrict__ e_t,
                                                const float* __restrict__ h_prev,
                                                const float* __restrict__ W_x,
                                                const float* __restrict__ W_h,
                                                const float* __restrict__ b_x,
                                                const float* __restrict__ b_h,
                                                const float* __restrict__ b_e,
                                                unsigned short* __restrict__ A_cat,
                                                unsigned short* __restrict__ W_cat,
                                                float* __restrict__ bias) {
    const int blk = blockIdx.x;
    const int t   = threadIdx.x;
    if (blk < NBLK_A + NBLK_W) {
        const float* src0;
        unsigned short* dst;
        int row;
        if (blk < NBLK_A) {
            row = blk;
            dst = A_cat + (size_t)row * KTOT;
            int c8 = t << 3;
            src0 = (c8 < DH) ? (e_t + (size_t)row * DH + c8)
                             : (h_prev + (size_t)row * DH + (c8 - DH));
        } else {
            row = blk - NBLK_A;                 // n in [0,4096)
            int gate = (row >> 4) & 3;
            int h    = (row >> 6) * 16 + (row & 15);
            int srow = gate * DH + h;
            dst = W_cat + (size_t)row * KTOT;
            int c8 = t << 3;
            src0 = (c8 < DH) ? (W_x + (size_t)srow * DH + c8)
                             : (W_h + (size_t)srow * DH + (c8 - DH));
        }
        float4 f0 = ((const float4*)src0)[0];
        float4 f1 = ((const float4*)src0)[1];
        uint4 o;
        o.x = (unsigned)f2bf(f0.x) | ((unsigned)f2bf(f0.y) << 16);
        o.y = (unsigned)f2bf(f0.z) | ((unsigned)f2bf(f0.w) << 16);
        o.z = (unsigned)f2bf(f1.x) | ((unsigned)f2bf(f1.y) << 16);
        o.w = (unsigned)f2bf(f1.z) | ((unsigned)f2bf(f1.w) << 16);
        *(uint4*)(dst + t * 8) = o;
    } else {
        int gp = (blk - NBLK_A - NBLK_W) * 256 + t;   // n in [0,4096)
        int gate = (gp >> 4) & 3;
        int h    = (gp >> 6) * 16 + (gp & 15);
        int g    = gate * DH + h;
        bias[gp] = b_x[g] + b_h[g] + b_e[g];
    }
}

// ---------- 256x256 8-wave GEMM, overlap-scheduled, + fused LSTM epilogue ----
//
// BM=BN=256, BK=64, 8 waves (2M x 4N), LDS 128 KiB (2-parity A/B buffers).
// XOR granule swizzle (verified): logical 16B-granule g of row r stored at
// physical p = g ^ (r&7); applied on the global SOURCE address
// (global_load_lds dest stays linear); fragment reads use
// p = (kk*4+quad) ^ (lane15&7).
//
// ROUND-3 RESTRUCTURE (fix for round-2's serialization): round 2 had 8
// barriers/tile, serializing the LDS-read segment (~2300 cyc/CU/tile) with
// the MFMA segment (~2483 cyc/CU/tile).  Only 2 sync points are load-bearing:
//   (a) all waves retired ALL tile-t ds_reads  -> staging t+2 into the same
//       parity buffers is safe  (barrier after per-wave lgkmcnt(0))
//   (b) tile t+1's GLLs complete in all waves  -> vmcnt(8) + barrier at end
// Everything else runs on counted per-wave lgkmcnt: issue all 24 ds_reads
// up front (grouped, sched_barrier(0) between groups to preserve oldest-N
// order), then lgkmcnt(12) -> MFMA loxlo, lgkmcnt(8) -> loxhi,
// lgkmcnt(0) -> [barrier, stage B+A(t+2)] -> hixlo, hixhi -> vmcnt(8),
// barrier.  LDS service of later reads hides under earlier MFMA clusters;
// vmcnt never drains to 0 in the main loop.

#define GLL(srcp, dstp) \
    __builtin_amdgcn_global_load_lds( \
        (const __attribute__((address_space(1))) void*)(srcp), \
        (__attribute__((address_space(3))) void*)(dstp), 16, 0, 0)

// one half-tile = 128 rows x 64 cols bf16 = 2 issues x (8 waves x 64 lanes x 16B)
#define STAGE_HALF(g, buf, h, kt) do { \
    GLL((g) + ((size_t)((h) * 128)      * KTOT) + (size_t)(kt) * 64, (buf) + (((h) * 128)      + w8) * 128); \
    GLL((g) + ((size_t)((h) * 128 + 64) * KTOT) + (size_t)(kt) * 64, (buf) + (((h) * 128 + 64) + w8) * 128); \
} while (0)

#define SB() __builtin_amdgcn_sched_barrier(0)

template <int MODE>  // 2 = steady  (stage t+2, vmcnt(8) + barrier at end)
                     // 1 = tile 30 (no staging, vmcnt(0) + barrier at end)
                     // 0 = tile 31 (no staging, no trailing sync)
__device__ __forceinline__ void do_tile(
    int kt,
    unsigned char* As_cur, unsigned char* Bs_cur,
    const unsigned short* __restrict__ gA, const unsigned short* __restrict__ gB,
    int w8, int rowA, int rowB, int xg0, int xg1,
    f32x4 (&acc)[8][4])
{
    bf16x8 afl[4][2], afh[4][2], bfl[2][2], bfh[2][2];

    // ---- issue ALL 24 ds_reads up front, in wait-group order ----
    // group 1 (oldest 12): afl(8) + bfl(4)
#pragma unroll
    for (int mi = 0; mi < 4; ++mi) {
        afl[mi][0] = *(const bf16x8*)(As_cur + rowA + mi * 2048 + xg0);
        afl[mi][1] = *(const bf16x8*)(As_cur + rowA + mi * 2048 + xg1);
    }
#pragma unroll
    for (int ni = 0; ni < 2; ++ni) {
        bfl[ni][0] = *(const bf16x8*)(Bs_cur + rowB + ni * 2048 + xg0);
        bfl[ni][1] = *(const bf16x8*)(Bs_cur + rowB + ni * 2048 + xg1);
    }
    SB();
    // group 2 (next 4): bfh
#pragma unroll
    for (int ni = 0; ni < 2; ++ni) {
        bfh[ni][0] = *(const bf16x8*)(Bs_cur + rowB + (2 + ni) * 2048 + xg0);
        bfh[ni][1] = *(const bf16x8*)(Bs_cur + rowB + (2 + ni) * 2048 + xg1);
    }
    SB();
    // group 3 (last 8): afh
#pragma unroll
    for (int mi = 0; mi < 4; ++mi) {
        afh[mi][0] = *(const bf16x8*)(As_cur + rowA + (4 + mi) * 2048 + xg0);
        afh[mi][1] = *(const bf16x8*)(As_cur + rowA + (4 + mi) * 2048 + xg1);
    }
    SB();

    // ---- cluster 1: lo x lo (needs afl+bfl = oldest 12) ----
    asm volatile("s_waitcnt lgkmcnt(12)" ::: "memory");
    SB();
    __builtin_amdgcn_s_setprio(1);
#pragma unroll
    for (int mi = 0; mi < 4; ++mi)
#pragma unroll
        for (int ni = 0; ni < 2; ++ni) {
            acc[mi][ni] = __builtin_amdgcn_mfma_f32_16x16x32_bf16(afl[mi][0], bfl[ni][0], acc[mi][ni], 0, 0, 0);
            acc[mi][ni] = __builtin_amdgcn_mfma_f32_16x16x32_bf16(afl[mi][1], bfl[ni][1], acc[mi][ni], 0, 0, 0);
        }
    __builtin_amdgcn_s_setprio(0);
    SB();

    // ---- cluster 2: lo x hi (needs bfh = oldest 16) ----
    asm volatile("s_waitcnt lgkmcnt(8)" ::: "memory");
    SB();
    __builtin_amdgcn_s_setprio(1);
#pragma unroll
    for (int mi = 0; mi < 4; ++mi)
#pragma unroll
        for (int ni = 0; ni < 2; ++ni) {
            acc[mi][2 + ni] = __builtin_amdgcn_mfma_f32_16x16x32_bf16(afl[mi][0], bfh[ni][0], acc[mi][2 + ni], 0, 0, 0);
            acc[mi][2 + ni] = __builtin_amdgcn_mfma_f32_16x16x32_bf16(afl[mi][1], bfh[ni][1], acc[mi][2 + ni], 0, 0, 0);
        }
    __builtin_amdgcn_s_setprio(0);
    SB();

    // ---- all reads retired; sync; stage tile kt+2 into current-parity bufs --
    asm volatile("s_waitcnt lgkmcnt(0)" ::: "memory");
    SB();
    if constexpr (MODE == 2) {
        __builtin_amdgcn_s_barrier();      // (a) every wave retired its reads
        SB();
        STAGE_HALF(gB, Bs_cur, 0, kt + 2);
        STAGE_HALF(gB, Bs_cur, 1, kt + 2);
        STAGE_HALF(gA, As_cur, 0, kt + 2);
        STAGE_HALF(gA, As_cur, 1, kt + 2);
        SB();
    }

    // ---- cluster 3: hi x lo ----
    __builtin_amdgcn_s_setprio(1);
#pragma unroll
    for (int mi = 0; mi < 4; ++mi)
#pragma unroll
        for (int ni = 0; ni < 2; ++ni) {
            acc[4 + mi][ni] = __builtin_amdgcn_mfma_f32_16x16x32_bf16(afh[mi][0], bfl[ni][0], acc[4 + mi][ni], 0, 0, 0);
            acc[4 + mi][ni] = __builtin_amdgcn_mfma_f32_16x16x32_bf16(afh[mi][1], bfl[ni][1], acc[4 + mi][ni], 0, 0, 0);
        }
    __builtin_amdgcn_s_setprio(0);

    // ---- cluster 4: hi x hi ----
    __builtin_amdgcn_s_setprio(1);
#pragma unroll
    for (int mi = 0; mi < 4; ++mi)
#pragma unroll
        for (int ni = 0; ni < 2; ++ni) {
            acc[4 + mi][2 + ni] = __builtin_amdgcn_mfma_f32_16x16x32_bf16(afh[mi][0], bfh[ni][0], acc[4 + mi][2 + ni], 0, 0, 0);
            acc[4 + mi][2 + ni] = __builtin_amdgcn_mfma_f32_16x16x32_bf16(afh[mi][1], bfh[ni][1], acc[4 + mi][2 + ni], 0, 0, 0);
        }
    __builtin_amdgcn_s_setprio(0);
    SB();

    // ---- (b) tile kt+1 resident before its reads begin ----
    if constexpr (MODE == 2) {
        asm volatile("s_waitcnt vmcnt(8)" ::: "memory");   // t+1's 8 GLLs done
        SB();
        __builtin_amdgcn_s_barrier();
        SB();
    } else if constexpr (MODE == 1) {
        asm volatile("s_waitcnt vmcnt(0)" ::: "memory");   // tile 31 resident
        SB();
        __builtin_amdgcn_s_barrier();
        SB();
    }
}

__global__ __launch_bounds__(512, 2) void lstm_gemm(
    const unsigned short* __restrict__ A,
    const unsigned short* __restrict__ Wc,
    const float* __restrict__ bias,
    const float* __restrict__ c_prev,
    float* __restrict__ h_out,
    float* __restrict__ c_out)
{
    __shared__ __align__(16) unsigned char lds[131072];

    const int tid = threadIdx.x;
    const int w   = tid >> 6;          // wave 0..7
    const int l   = tid & 63;          // lane
    const int wm  = w >> 2, wn = w & 3;
    const int m0  = blockIdx.y * 256;
    const int n0  = blockIdx.x * 256;
    const int w8  = w * 8;

    f32x4 acc[8][4];
#pragma unroll
    for (int i = 0; i < 8; ++i)
#pragma unroll
        for (int j = 0; j < 4; ++j) acc[i][j] = {0.f, 0.f, 0.f, 0.f};

    // staging: wave w, lane l -> tile row = base + w*8 + (l>>3),
    // physical granule p = l&7, pre-swizzled source granule g = p ^ (row&7)
    const int srow = w8 + (l >> 3);
    const int scol = ((l & 7) ^ ((l >> 3) & 7)) * 8;   // element offset in 64-wide K-tile
    const unsigned short* gA = A  + (size_t)(m0 + srow) * KTOT + scol;
    const unsigned short* gB = Wc + (size_t)(n0 + srow) * KTOT + scol;

    unsigned char* As0 = lds;
    unsigned char* As1 = lds + 32768;
    unsigned char* Bs0 = lds + 65536;
    unsigned char* Bs1 = lds + 98304;

    const int lane15 = l & 15;
    const int quad   = l >> 4;
    const int rowA = (wm * 128 + lane15) * 128;   // byte offset of A fragment row base
    const int rowB = (wn * 64  + lane15) * 128;
    const int xg0  = ((0 + quad) ^ (lane15 & 7)) * 16;   // kk=0 swizzled granule
    const int xg1  = ((4 + quad) ^ (lane15 & 7)) * 16;   // kk=1

    // ---- prologue: stage tile0 -> parity-0 bufs, tile1 -> parity-1 bufs ----
    STAGE_HALF(gA, As0, 0, 0);
    STAGE_HALF(gA, As0, 1, 0);
    STAGE_HALF(gB, Bs0, 0, 0);
    STAGE_HALF(gB, Bs0, 1, 0);
    STAGE_HALF(gA, As1, 0, 1);
    STAGE_HALF(gA, As1, 1, 1);
    STAGE_HALF(gB, Bs1, 0, 1);
    STAGE_HALF(gB, Bs1, 1, 1);
    SB();
    asm volatile("s_waitcnt vmcnt(8)" ::: "memory");   // tile0 fully resident
    SB();
    __builtin_amdgcn_s_barrier();
    SB();

#pragma unroll 1
    for (int kt2 = 0; kt2 < 15; ++kt2) {
        do_tile<2>(2 * kt2,     As0, Bs0, gA, gB, w8, rowA, rowB, xg0, xg1, acc);
        do_tile<2>(2 * kt2 + 1, As1, Bs1, gA, gB, w8, rowA, rowB, xg0, xg1, acc);
    }
    do_tile<1>(30, As0, Bs0, gA, gB, w8, rowA, rowB, xg0, xg1, acc);
    do_tile<0>(31, As1, Bs1, gA, gB, w8, rowA, rowB, xg0, xg1, acc);

    // ---------- fused LSTM epilogue (shuffle-free via gate-deinterleave) ----
    // C/D layout: col = lane&15 (n), row = quad*4 + reg (m).
    // N-packing puts gate = nj, h = ((n0+wn*64)>>6)*16 + lane15 for this wave:
    // acc[mi][0..3] are (zf,zi,zo,zc) of the SAME h, for 4 consecutive m rows.
    float biasv[4];
#pragma unroll
    for (int nj = 0; nj < 4; ++nj)
        biasv[nj] = bias[n0 + wn * 64 + nj * 16 + lane15];

    const int hcol = ((n0 + wn * 64) >> 6) * 16 + lane15;   // h index for this lane

#pragma unroll
    for (int mi = 0; mi < 8; ++mi) {
        const int mbase = m0 + wm * 128 + mi * 16 + quad * 4;
        f32x4 zf4 = acc[mi][0];
        f32x4 zi4 = acc[mi][1];
        f32x4 zo4 = acc[mi][2];
        f32x4 zc4 = acc[mi][3];
#pragma unroll
        for (int r = 0; r < 4; ++r) {
            float zf = zf4[r] + biasv[0];
            float zi = zi4[r] + biasv[1];
            float zo = zo4[r] + biasv[2];
            float zc = zc4[r] + biasv[3];

            float gf = fast_sigmoid(zf);
            float gi = fast_sigmoid(zi);
            float go = fast_sigmoid(zo);
            float mh = fast_tanh(zc);

            const size_t off = (size_t)(mbase + r) * DH + hcol;
            float cp = c_prev[off];
            float ct = gf * cp + gi * mh;
            float ht = go * fast_tanh(ct);
            h_out[off] = ht;
            c_out[off] = ct;
        }
    }
}

// ---------- launch ----------
extern "C" void kernel_launch(void* const* d_in, const int* in_sizes, int n_in,
                              void* d_out, int out_size, void* d_ws, size_t ws_size,
                              hipStream_t stream) {
    const float* e_t     = (const float*)d_in[0];
    const float* h_prev  = (const float*)d_in[1];
    const float* c_prev  = (const float*)d_in[2];
    const float* W_x     = (const float*)d_in[3];
    const float* b_x     = (const float*)d_in[4];
    const float* W_h     = (const float*)d_in[5];
    const float* b_h     = (const float*)d_in[6];
    const float* b_extra = (const float*)d_in[7];

    float* h_out = (float*)d_out;
    float* c_out = h_out + (size_t)B_ROWS * DH;

    // workspace layout: A_cat (32MB) | W_cat (16MB) | bias (16KB)
    unsigned short* A_cat = (unsigned short*)d_ws;
    unsigned short* W_cat = (unsigned short*)((char*)d_ws + (size_t)B_ROWS * KTOT * 2);
    float*          bias  = (float*)((char*)d_ws + (size_t)B_ROWS * KTOT * 2 + (size_t)NTOT * KTOT * 2);

    pack_all<<<NBLK_A + NBLK_W + NBLK_BIAS, 256, 0, stream>>>(
        e_t, h_prev, W_x, W_h, b_x, b_h, b_extra, A_cat, W_cat, bias);
    lstm_gemm<<<dim3(NTOT / 256, B_ROWS / 256), 512, 0, stream>>>(
        A_cat, W_cat, bias, c_prev, h_out, c_out);
}